// Round 14
// baseline (698.065 us; speedup 1.0000x reference)
//
#include <hip/hip_runtime.h>
#include <hip/hip_fp16.h>

#define N_NODES 100000
#define N_EDGES 1600000
#define BN_EPS 1e-5f

#define NBUCK 1024         // dst buckets (slots allocated)
#define NPB   98           // nodes per bucket
#define NBUCK_USED ((N_NODES + NPB - 1) / NPB)   // 1021
#define BCAP  2048         // edge capacity per bucket (mean 1563, +12 sigma)
#define EPB_BIN 4096       // edges per k_bin block
#define NBLK_BIN ((N_EDGES + EPB_BIN - 1) / EPB_BIN)   // 391
#define ACC_STRIDE 66      // padded row stride for LDS accum (bank spread)

#define K7_NBLK 1563       // k7_xw2 grid: 6250 groups / 4 waves per block

// ---- workspace layout (32-bit units) ----
#define OFF_GCUR   0            // 1024 ints: bucket fill cursors
#define OFF_STATS1 1024         // 128 floats: sum[64], sumsq[64]
#define OFF_STATS2 1152         // 4 floats
#define OFF_DINV   1280         // N floats
#define OFF_BINNED 101376       // NBUCK*BCAP = 2,097,152 ints (persistent!)
#define OFF_HS1    2198528      // half[N*64] = 3.2M u32
#define OFF_OUT1   5398528      // half[N*64] = 3.2M u32
#define OFF_HS2    8598528      // N*2 floats
#define OFF_OUT2   8798528      // N*2 floats
// total 8,998,528 * 4B = 36.0 MB

typedef _Float16 f16x8 __attribute__((ext_vector_type(8)));
typedef float    f32x4 __attribute__((ext_vector_type(4)));

__device__ inline void cvt8(uint4 v, float* f) {
    float2 a = __half22float2(*(__half2*)&v.x);
    float2 b = __half22float2(*(__half2*)&v.y);
    float2 c = __half22float2(*(__half2*)&v.z);
    float2 d = __half22float2(*(__half2*)&v.w);
    f[0] = a.x; f[1] = a.y; f[2] = b.x; f[3] = b.y;
    f[4] = c.x; f[5] = c.y; f[6] = d.x; f[7] = d.y;
}

// K0: init bucket cursors to slice bases; zero stat accumulators
__global__ __launch_bounds__(1024) void k0_init(int* __restrict__ gcur,
                                                float* __restrict__ stats) {
    int t = threadIdx.x;
    gcur[t] = t * BCAP;
    if (t < 132) stats[t] = 0.f;   // stats1(128)+stats2(4) contiguous
}

// K1: radix partition edges into 1024 dst-buckets; packed (src | ldst<<17)
__global__ __launch_bounds__(256) void k_bin(
        const int* __restrict__ src, const int* __restrict__ dst,
        int* __restrict__ gcur, int* __restrict__ binned) {
    __shared__ int hist[NBUCK];
    __shared__ int lcur[NBUCK];
    int t = threadIdx.x, b = blockIdx.x;
#pragma unroll
    for (int i = 0; i < 4; ++i) hist[t + i * 256] = 0;
    __syncthreads();
    int e0 = b * EPB_BIN;
    int pkreg[16], bkreg[16];
#pragma unroll
    for (int i = 0; i < 16; ++i) {
        int e = e0 + t + i * 256;              // coalesced
        if (e < N_EDGES) {
            int s = src[e], d = dst[e];
            int bk = d / NPB;
            bkreg[i] = bk;
            pkreg[i] = s | ((d - bk * NPB) << 17);
            atomicAdd(&hist[bk], 1);
        } else bkreg[i] = -1;
    }
    __syncthreads();
#pragma unroll
    for (int i = 0; i < 4; ++i) {
        int slot = t + i * 256;
        int h = hist[slot];
        lcur[slot] = (h > 0) ? atomicAdd(&gcur[slot], h) : 0;
    }
    __syncthreads();
#pragma unroll
    for (int i = 0; i < 16; ++i) {
        if (bkreg[i] >= 0) {
            int bk = bkreg[i];
            int pos = atomicAdd(&lcur[bk], 1);
            if (pos < (bk + 1) * BCAP)          // overflow guard (never taken)
                binned[pos] = pkreg[i];
        }
    }
}

// K2: per-bucket degree -> dinv (1 LDS atomic per edge)
__global__ __launch_bounds__(256) void k_deg(
        const int* __restrict__ gcur, const int* __restrict__ binned,
        float* __restrict__ dinv) {
    int b = blockIdx.x, t = threadIdx.x;
    int nb0 = b * NPB;
    if (nb0 >= N_NODES) return;
    int nn = min(NPB, N_NODES - nb0);
    __shared__ int lcnt[NPB];
    for (int i = t; i < NPB; i += 256) lcnt[i] = 0;
    __syncthreads();
    int base = b * BCAP;
    int m = min(gcur[b] - base, BCAP);
    for (int j = t; j < m; j += 256)
        atomicAdd(&lcnt[((unsigned)binned[base + j]) >> 17], 1);
    __syncthreads();
    for (int i = t; i < nn; i += 256)
        dinv[nb0 + i] = rsqrtf((float)(1 + lcnt[i]));
}

// K3: hs1 = fp16( (u_S @ w1) * dinv[row] ) via MFMA.
__global__ __launch_bounds__(256) void k3_xw1(
        const float* __restrict__ u, const float* __restrict__ w1g,
        const float* __restrict__ dinv, __half* __restrict__ hs1) {
    int t = threadIdx.x;
    int lane = t & 63, wid = t >> 6;
    int g = blockIdx.x * 4 + wid;              // 16-row group id
    if (g >= N_NODES / 16) return;             // wave-uniform exit
    int r = lane & 15, kb = lane >> 4;

    f16x8 bf[4][2];                            // [col-tile][k-half]
#pragma unroll
    for (int ct = 0; ct < 4; ++ct) {
#pragma unroll
        for (int kh = 0; kh < 2; ++kh) {
            int c = ct * 16 + r;
            int k0 = kh * 32 + kb * 8;
            f16x8 b;
#pragma unroll
            for (int i = 0; i < 8; ++i) b[i] = (_Float16)w1g[(k0 + i) * 64 + c];
            bf[ct][kh] = b;
        }
    }

    const float* up = u + (size_t)g * 16 * 64;
    f16x8 af[2];
#pragma unroll
    for (int kh = 0; kh < 2; ++kh) {
        const float* p = up + r * 64 + kh * 32 + kb * 8;
        float4 v0 = *(const float4*)p;
        float4 v1 = *(const float4*)(p + 4);
        f16x8 a;
        a[0] = (_Float16)v0.x; a[1] = (_Float16)v0.y;
        a[2] = (_Float16)v0.z; a[3] = (_Float16)v0.w;
        a[4] = (_Float16)v1.x; a[5] = (_Float16)v1.y;
        a[6] = (_Float16)v1.z; a[7] = (_Float16)v1.w;
        af[kh] = a;
    }

    f32x4 acc[4];
#pragma unroll
    for (int ct = 0; ct < 4; ++ct) { acc[ct][0]=0.f; acc[ct][1]=0.f; acc[ct][2]=0.f; acc[ct][3]=0.f; }
#pragma unroll
    for (int ct = 0; ct < 4; ++ct) {
        acc[ct] = __builtin_amdgcn_mfma_f32_16x16x32_f16(af[0], bf[ct][0], acc[ct], 0, 0, 0);
        acc[ct] = __builtin_amdgcn_mfma_f32_16x16x32_f16(af[1], bf[ct][1], acc[ct], 0, 0, 0);
    }

    int r0 = g * 16;
    float4 dv = *(const float4*)&dinv[r0 + kb * 4];
    float dvv[4] = {dv.x, dv.y, dv.z, dv.w};
#pragma unroll
    for (int ct = 0; ct < 4; ++ct) {
#pragma unroll
        for (int reg = 0; reg < 4; ++reg) {
            int row = r0 + kb * 4 + reg;
            int col = ct * 16 + r;
            hs1[(size_t)row * 64 + col] = __float2half(acc[ct][reg] * dvv[reg]);
        }
    }
}

// K4: layer-1 aggregation, push-into-LDS per bucket + fused BN1 stats.
// 8 lanes/edge gather hs1[src] (uint4), atomicAdd into LDS tile.
__global__ __launch_bounds__(256) void k_pull1B(
        const int* __restrict__ gcur, const int* __restrict__ binned,
        const float* __restrict__ dinv, const __half* __restrict__ hs1,
        __half* __restrict__ out1, float* __restrict__ stats) {
    int b = blockIdx.x, t = threadIdx.x;
    int nb0 = b * NPB;
    if (nb0 >= N_NODES) return;
    int nn = min(NPB, N_NODES - nb0);
    __shared__ float acc[NPB * ACC_STRIDE];    // 25,872 B
    for (int i = t; i < NPB * ACC_STRIDE; i += 256) acc[i] = 0.f;
    __syncthreads();
    const uint4* h8 = (const uint4*)hs1;
    int base = b * BCAP;
    int m = min(gcur[b] - base, BCAP);
    int subl = t & 7;
    for (int j = t >> 3; j < m; j += 32) {     // 32 edges in flight per block
        unsigned v = (unsigned)binned[base + j];
        int s = v & 0x1FFFF;
        int ld = v >> 17;
        float f[8];
        cvt8(h8[s * 8 + subl], f);
        float* a = &acc[ld * ACC_STRIDE + subl * 8];
#pragma unroll
        for (int k = 0; k < 8; ++k) atomicAdd(&a[k], f[k]);
    }
    __syncthreads();
    // epilogue: self-loop + dinv scale + fp16 write + stats partials
    float ps[8] = {0,0,0,0,0,0,0,0}, pq[8] = {0,0,0,0,0,0,0,0};
    for (int i = t >> 3; i < nn; i += 32) {
        int d = nb0 + i;
        float f[8];
        cvt8(h8[d * 8 + subl], f);             // self-loop term
        float di = dinv[d];
        const float* a = &acc[i * ACC_STRIDE + subl * 8];
        float o[8];
#pragma unroll
        for (int k = 0; k < 8; ++k) {
            o[k] = (a[k] + f[k]) * di;
            ps[k] += o[k];
            pq[k] = fmaf(o[k], o[k], pq[k]);
        }
        __half2 p0 = __floats2half2_rn(o[0], o[1]);
        __half2 p1 = __floats2half2_rn(o[2], o[3]);
        __half2 p2 = __floats2half2_rn(o[4], o[5]);
        __half2 p3 = __floats2half2_rn(o[6], o[7]);
        uint4 w; w.x = *(unsigned*)&p0; w.y = *(unsigned*)&p1;
        w.z = *(unsigned*)&p2; w.w = *(unsigned*)&p3;
        ((uint4*)out1)[d * 8 + subl] = w;
    }
    // reduce: 8 lanes per wave share subl (xor bits 3..5), then cross-wave
#pragma unroll
    for (int mm = 8; mm < 64; mm <<= 1) {
#pragma unroll
        for (int k = 0; k < 8; ++k) {
            ps[k] += __shfl_xor(ps[k], mm);
            pq[k] += __shfl_xor(pq[k], mm);
        }
    }
    __shared__ float red[4][128];
    int lane = t & 63, wv = t >> 6;
    if (lane < 8) {
        int c0 = lane * 8;
#pragma unroll
        for (int k = 0; k < 8; ++k) {
            red[wv][c0 + k] = ps[k];
            red[wv][64 + c0 + k] = pq[k];
        }
    }
    __syncthreads();
    if (t < 128) {
        float v = red[0][t] + red[1][t] + red[2][t] + red[3][t];
        unsafeAtomicAdd(&stats[t], v);         // stats[c]=sum, stats[64+c]=sumsq
    }
}

// K5: s1 = relu(bn1(out1)); hs2 = (s1 @ w2) * dinv[row], via MFMA.
__global__ __launch_bounds__(256) void k7_xw2(
        const __half* __restrict__ out1, const float* __restrict__ stats,
        const float* __restrict__ g1, const float* __restrict__ beta1,
        const float* __restrict__ w2, const float* __restrict__ dinv,
        float* __restrict__ hs2) {
    __shared__ float lsc[64], lsh[64];
    int t = threadIdx.x;
    if (t < 64) {
        float invn = 1.f / (float)N_NODES;
        float m = stats[t] * invn;
        float v = stats[64 + t] * invn - m * m;
        float inv = rsqrtf(v + BN_EPS);
        float sc = g1[t] * inv;
        lsc[t] = sc;
        lsh[t] = beta1[t] - m * sc;
    }
    __syncthreads();
    int lane = t & 63, wv = t >> 6;
    int r = lane & 15, kb = lane >> 4;
    f16x8 bf[2];
    float scr[2][8], shr[2][8];
#pragma unroll
    for (int kh = 0; kh < 2; ++kh) {
        int k0 = kh * 32 + kb * 8;
        f16x8 b;
#pragma unroll
        for (int i = 0; i < 8; ++i) {
            b[i] = (r < 2) ? (_Float16)w2[(k0 + i) * 2 + r] : (_Float16)0.f;
            scr[kh][i] = lsc[k0 + i];
            shr[kh][i] = lsh[k0 + i];
        }
        bf[kh] = b;
    }
    const int NGRP = N_NODES / 16;             // 6250
    int wid = blockIdx.x * 4 + wv;
    for (int g = wid; g < NGRP; g += K7_NBLK * 4) {
        f32x4 acc; acc[0]=0.f; acc[1]=0.f; acc[2]=0.f; acc[3]=0.f;
#pragma unroll
        for (int kh = 0; kh < 2; ++kh) {
            uint4 av = *(const uint4*)(out1 + (size_t)(g * 16 + r) * 64 + kh * 32 + kb * 8);
            unsigned w[4] = {av.x, av.y, av.z, av.w};
            f16x8 a;
#pragma unroll
            for (int h = 0; h < 4; ++h) {
                float2 f = __half22float2(*(__half2*)&w[h]);
                float y0 = fmaxf(fmaf(f.x, scr[kh][2*h],   shr[kh][2*h]),   0.f);
                float y1 = fmaxf(fmaf(f.y, scr[kh][2*h+1], shr[kh][2*h+1]), 0.f);
                a[2*h]   = (_Float16)y0;
                a[2*h+1] = (_Float16)y1;
            }
            acc = __builtin_amdgcn_mfma_f32_16x16x32_f16(a, bf[kh], acc, 0, 0, 0);
        }
        if (r < 2) {
            float4 dv = *(const float4*)&dinv[g * 16 + kb * 4];
            float dvv[4] = {dv.x, dv.y, dv.z, dv.w};
#pragma unroll
            for (int reg = 0; reg < 4; ++reg) {
                int row = g * 16 + kb * 4 + reg;
                hs2[row * 2 + r] = acc[reg] * dvv[reg];
            }
        }
    }
}

// K6: layer-2 aggregation, push-into-LDS per bucket + fused BN2 stats
__global__ __launch_bounds__(256) void k_pull2B(
        const int* __restrict__ gcur, const int* __restrict__ binned,
        const float* __restrict__ dinv, const float* __restrict__ hs2,
        float* __restrict__ out2, float* __restrict__ stats2) {
    int b = blockIdx.x, t = threadIdx.x;
    int nb0 = b * NPB;
    if (nb0 >= N_NODES) return;
    int nn = min(NPB, N_NODES - nb0);
    __shared__ float a0[NPB], a1[NPB];
    for (int i = t; i < NPB; i += 256) { a0[i] = 0.f; a1[i] = 0.f; }
    __syncthreads();
    int base = b * BCAP;
    int m = min(gcur[b] - base, BCAP);
    const float2* h2 = (const float2*)hs2;
    for (int j = t; j < m; j += 256) {         // coalesced binned read
        unsigned v = (unsigned)binned[base + j];
        float2 x = h2[v & 0x1FFFF];            // L2-resident gather (800KB)
        int ld = v >> 17;
        atomicAdd(&a0[ld], x.x);
        atomicAdd(&a1[ld], x.y);
    }
    __syncthreads();
    float s0 = 0.f, s1 = 0.f, q0 = 0.f, q1 = 0.f;
    for (int i = t; i < nn; i += 256) {
        int d = nb0 + i;
        float2 self = h2[d];
        float di = dinv[d];
        float o0 = (a0[i] + self.x) * di;
        float o1 = (a1[i] + self.y) * di;
        ((float2*)out2)[d] = make_float2(o0, o1);
        s0 += o0; s1 += o1;
        q0 = fmaf(o0, o0, q0); q1 = fmaf(o1, o1, q1);
    }
#pragma unroll
    for (int mm = 32; mm; mm >>= 1) {
        s0 += __shfl_down(s0, mm); s1 += __shfl_down(s1, mm);
        q0 += __shfl_down(q0, mm); q1 += __shfl_down(q1, mm);
    }
    __shared__ float red[4][4];
    int wv = t >> 6;
    if ((t & 63) == 0) {
        red[0][wv] = s0; red[1][wv] = s1; red[2][wv] = q0; red[3][wv] = q1;
    }
    __syncthreads();
    if (t < 4) {
        float v = red[t][0] + red[t][1] + red[t][2] + red[t][3];
        unsafeAtomicAdd(&stats2[t], v);
    }
}

// K7: BN2 + sigmoid + softmax epilogue
__global__ __launch_bounds__(256) void k10_head(
        const float* __restrict__ out2, const float* __restrict__ stats2,
        const float* __restrict__ g2, const float* __restrict__ beta2,
        float* __restrict__ out) {
    int r = blockIdx.x * blockDim.x + threadIdx.x;
    if (r >= N_NODES) return;
    float invn = 1.f / (float)N_NODES;
    float m0 = stats2[0] * invn, m1 = stats2[1] * invn;
    float v0 = stats2[2] * invn - m0 * m0;
    float v1 = stats2[3] * invn - m1 * m1;
    float i0 = rsqrtf(v0 + BN_EPS), i1 = rsqrtf(v1 + BN_EPS);
    float sc0 = g2[0] * i0, sc1 = g2[1] * i1;
    float sh0 = beta2[0] - m0 * sc0, sh1 = beta2[1] - m1 * sc1;
    float2 x = ((const float2*)out2)[r];
    float y0 = fmaf(x.x, sc0, sh0), y1 = fmaf(x.y, sc1, sh1);
    out[r * 2] = 1.f / (1.f + __expf(-y0));
    out[r * 2 + 1] = 1.f / (1.f + __expf(-y1));
    out[2 * N_NODES + r * 2] = 1.f / (1.f + __expf(y1 - y0));
    out[2 * N_NODES + r * 2 + 1] = 1.f / (1.f + __expf(y0 - y1));
}

extern "C" void kernel_launch(void* const* d_in, const int* in_sizes, int n_in,
                              void* d_out, int out_size, void* d_ws, size_t ws_size,
                              hipStream_t stream) {
    const int*   edge  = (const int*)d_in[0];          // (2,E): [0,E)=src, [E,2E)=dst
    const float* u_S   = (const float*)d_in[1];
    const float* w1    = (const float*)d_in[2];
    const float* g1    = (const float*)d_in[4];
    const float* beta1 = (const float*)d_in[5];
    const float* w2    = (const float*)d_in[6];
    const float* g2    = (const float*)d_in[8];
    const float* beta2 = (const float*)d_in[9];
    float* out = (float*)d_out;

    float*  ws     = (float*)d_ws;
    int*    gcur   = (int*)(ws + OFF_GCUR);
    float*  stats1 = ws + OFF_STATS1;
    float*  stats2 = ws + OFF_STATS2;
    float*  dinv   = ws + OFF_DINV;
    int*    binned = (int*)(ws + OFF_BINNED);
    __half* hs1    = (__half*)(ws + OFF_HS1);
    __half* out1   = (__half*)(ws + OFF_OUT1);
    float*  hs2    = ws + OFF_HS2;
    float*  out2   = ws + OFF_OUT2;

    const int* src = edge;
    const int* dst = edge + N_EDGES;

    k0_init<<<1, 1024, 0, stream>>>(gcur, stats1);
    k_bin<<<NBLK_BIN, 256, 0, stream>>>(src, dst, gcur, binned);
    k_deg<<<NBUCK_USED, 256, 0, stream>>>(gcur, binned, dinv);
    k3_xw1<<<(N_NODES / 16 + 3) / 4, 256, 0, stream>>>(u_S, w1, dinv, hs1);
    k_pull1B<<<NBUCK_USED, 256, 0, stream>>>(gcur, binned, dinv, hs1, out1, stats1);
    k7_xw2<<<K7_NBLK, 256, 0, stream>>>(out1, stats1, g1, beta1, w2, dinv, hs2);
    k_pull2B<<<NBUCK_USED, 256, 0, stream>>>(gcur, binned, dinv, hs2, out2, stats2);
    k10_head<<<(N_NODES + 255) / 256, 256, 0, stream>>>(out2, stats2, g2, beta2, out);
}

// Round 16
// 235.760 us; speedup vs baseline: 2.9609x; 2.9609x over previous
//
#include <hip/hip_runtime.h>
#include <hip/hip_fp16.h>

#define N_NODES 100000
#define N_EDGES 1600000
#define BN_EPS 1e-5f

#define NBUCK 1024         // dst buckets
#define NPB   98           // nodes per bucket
#define NBUCK_USED ((N_NODES + NPB - 1) / NPB)   // 1021
#define BCAP  2048         // edge capacity per bucket (mean 1563, +12 sigma)
#define EPB_BIN 8192       // edges per k_bin block (two-pass read)
#define NBLK_BIN ((N_EDGES + EPB_BIN - 1) / EPB_BIN)   // 196

#define K7_NBLK 1563       // k7_xw2 grid

// ---- workspace layout (32-bit units) ----
#define OFF_GCUR   0            // 1024 ints: bucket fill cursors
#define OFF_STATS1 1024         // 128 floats: sum[64], sumsq[64]
#define OFF_STATS2 1152         // 4 floats
#define OFF_DINV   1280         // N floats
#define OFF_BINNED 101376       // NBUCK*BCAP = 2,097,152 ints
#define OFF_HS1    2198528      // half[N*64] = 3.2M u32
#define OFF_OUT1   5398528      // half[N*64] = 3.2M u32
#define OFF_HS2    8598528      // N*2 floats
#define OFF_OUT2   8798528      // N*2 floats
// total 8,998,528 * 4B = 36.0 MB

typedef _Float16 f16x8 __attribute__((ext_vector_type(8)));
typedef float    f32x4 __attribute__((ext_vector_type(4)));

__device__ inline void cvt8(uint4 v, float* f) {
    float2 a = __half22float2(*(__half2*)&v.x);
    float2 b = __half22float2(*(__half2*)&v.y);
    float2 c = __half22float2(*(__half2*)&v.z);
    float2 d = __half22float2(*(__half2*)&v.w);
    f[0] = a.x; f[1] = a.y; f[2] = b.x; f[3] = b.y;
    f[4] = c.x; f[5] = c.y; f[6] = d.x; f[7] = d.y;
}

// K0: init bucket cursors to slice bases; zero stat accumulators
__global__ __launch_bounds__(256) void k0_init(int* __restrict__ gcur,
                                               float* __restrict__ stats) {
    int t = threadIdx.x;
    for (int i = t; i < NBUCK; i += 256) gcur[i] = i * BCAP;
    if (t < 132) stats[t] = 0.f;   // stats1(128)+stats2(4) contiguous
}

// K1: radix partition edges into 1024 dst-buckets (two-pass; no edge regs).
__global__ __launch_bounds__(256) void k_bin(
        const int* __restrict__ src, const int* __restrict__ dst,
        int* __restrict__ gcur, int* __restrict__ binned) {
    __shared__ int hist[NBUCK];
    __shared__ int lcur[NBUCK];
    int t = threadIdx.x, b = blockIdx.x;
    for (int i = t; i < NBUCK; i += 256) hist[i] = 0;
    __syncthreads();
    int e0 = b * EPB_BIN;
    int e1 = min(e0 + EPB_BIN, N_EDGES);
    for (int e = e0 + t; e < e1; e += 256)
        atomicAdd(&hist[dst[e] / NPB], 1);
    __syncthreads();
    for (int i = t; i < NBUCK; i += 256) {
        int h = hist[i];
        lcur[i] = (h > 0) ? atomicAdd(&gcur[i], h) : 0;
    }
    __syncthreads();
    for (int e = e0 + t; e < e1; e += 256) {   // re-read (L2-hot)
        int s = src[e], d = dst[e];
        int bk = d / NPB;
        int pos = atomicAdd(&lcur[bk], 1);
        if (pos < (bk + 1) * BCAP)             // overflow guard (never taken)
            binned[pos] = s | ((d - bk * NPB) << 17);
    }
}

// K2: per-bucket degree -> dinv (LDS histogram only)
__global__ __launch_bounds__(256) void k_deg(
        const int* __restrict__ gcur, const int* __restrict__ binned,
        float* __restrict__ dinv) {
    int b = blockIdx.x, t = threadIdx.x;
    int nb0 = b * NPB;
    if (nb0 >= N_NODES) return;
    int nn = min(NPB, N_NODES - nb0);
    __shared__ int lcnt[NPB];
    for (int i = t; i < NPB; i += 256) lcnt[i] = 0;
    __syncthreads();
    int base = b * BCAP;
    int m = min(gcur[b] - base, BCAP);
    for (int j = t; j < m; j += 256)
        atomicAdd(&lcnt[((unsigned)binned[base + j]) >> 17], 1);
    __syncthreads();
    for (int i = t; i < nn; i += 256)
        dinv[nb0 + i] = rsqrtf((float)(1 + lcnt[i]));
}

// K3: hs1 = fp16( (u_S @ w1) * dinv[row] ) via MFMA.
__global__ __launch_bounds__(256) void k3_xw1(
        const float* __restrict__ u, const float* __restrict__ w1g,
        const float* __restrict__ dinv, __half* __restrict__ hs1) {
    int t = threadIdx.x;
    int lane = t & 63, wid = t >> 6;
    int g = blockIdx.x * 4 + wid;              // 16-row group id
    if (g >= N_NODES / 16) return;             // wave-uniform exit
    int r = lane & 15, kb = lane >> 4;

    f16x8 bf[4][2];                            // [col-tile][k-half]
#pragma unroll
    for (int ct = 0; ct < 4; ++ct) {
#pragma unroll
        for (int kh = 0; kh < 2; ++kh) {
            int c = ct * 16 + r;
            int k0 = kh * 32 + kb * 8;
            f16x8 b;
#pragma unroll
            for (int i = 0; i < 8; ++i) b[i] = (_Float16)w1g[(k0 + i) * 64 + c];
            bf[ct][kh] = b;
        }
    }

    const float* up = u + (size_t)g * 16 * 64;
    f16x8 af[2];
#pragma unroll
    for (int kh = 0; kh < 2; ++kh) {
        const float* p = up + r * 64 + kh * 32 + kb * 8;
        float4 v0 = *(const float4*)p;
        float4 v1 = *(const float4*)(p + 4);
        f16x8 a;
        a[0] = (_Float16)v0.x; a[1] = (_Float16)v0.y;
        a[2] = (_Float16)v0.z; a[3] = (_Float16)v0.w;
        a[4] = (_Float16)v1.x; a[5] = (_Float16)v1.y;
        a[6] = (_Float16)v1.z; a[7] = (_Float16)v1.w;
        af[kh] = a;
    }

    f32x4 acc[4];
#pragma unroll
    for (int ct = 0; ct < 4; ++ct) { acc[ct][0]=0.f; acc[ct][1]=0.f; acc[ct][2]=0.f; acc[ct][3]=0.f; }
#pragma unroll
    for (int ct = 0; ct < 4; ++ct) {
        acc[ct] = __builtin_amdgcn_mfma_f32_16x16x32_f16(af[0], bf[ct][0], acc[ct], 0, 0, 0);
        acc[ct] = __builtin_amdgcn_mfma_f32_16x16x32_f16(af[1], bf[ct][1], acc[ct], 0, 0, 0);
    }

    int r0 = g * 16;
    float4 dv = *(const float4*)&dinv[r0 + kb * 4];
    float dvv[4] = {dv.x, dv.y, dv.z, dv.w};
#pragma unroll
    for (int ct = 0; ct < 4; ++ct) {
#pragma unroll
        for (int reg = 0; reg < 4; ++reg) {
            int row = r0 + kb * 4 + reg;
            int col = ct * 16 + r;
            hs1[(size_t)row * 64 + col] = __float2half(acc[ct][reg] * dvv[reg]);
        }
    }
}

// K4: layer-1 aggregation. In-LDS counting sort of the bucket's edges, then
// round-12-style register gather (8 lanes/node, uint4), fused BN1 stats.
// NO LDS float atomics (round-14 lesson).
__global__ __launch_bounds__(256) void k_pull1C(
        const int* __restrict__ gcur, const int* __restrict__ binned,
        const float* __restrict__ dinv, const __half* __restrict__ hs1,
        __half* __restrict__ out1, float* __restrict__ stats) {
    int b = blockIdx.x, t = threadIdx.x;
    int nb0 = b * NPB;
    if (nb0 >= N_NODES) return;
    int nn = min(NPB, N_NODES - nb0);
    __shared__ int els[BCAP];                  // 8 KB: sorted src ids
    __shared__ int lcnt[NPB], loff[NPB], lcur2[NPB];
    __shared__ int sc[256];
    for (int i = t; i < NPB; i += 256) lcnt[i] = 0;
    __syncthreads();
    int base = b * BCAP;
    int m = min(gcur[b] - base, BCAP);
    for (int j = t; j < m; j += 256)
        atomicAdd(&lcnt[((unsigned)binned[base + j]) >> 17], 1);
    __syncthreads();
    sc[t] = (t < nn) ? lcnt[t] : 0;            // Hillis-Steele inclusive scan
    __syncthreads();
    for (int off = 1; off < 256; off <<= 1) {
        int v = (t >= off) ? sc[t - off] : 0;
        __syncthreads();
        sc[t] += v;
        __syncthreads();
    }
    if (t < nn) { int e = sc[t] - lcnt[t]; loff[t] = e; lcur2[t] = e; }
    __syncthreads();
    for (int j = t; j < m; j += 256) {         // scatter global->LDS (L2-hot)
        unsigned v = (unsigned)binned[base + j];
        int pos = atomicAdd(&lcur2[v >> 17], 1);
        els[pos] = (int)(v & 0x1FFFFu);
    }
    __syncthreads();
    // pull phase: 8 lanes/node gather from hs1, accumulate in registers
    const uint4* h8 = (const uint4*)hs1;
    int subl = t & 7, grp = t >> 3;
    float ps[8] = {0,0,0,0,0,0,0,0}, pq[8] = {0,0,0,0,0,0,0,0};
    for (int i = grp; i < nn; i += 32) {
        int d = nb0 + i;
        float acc[8];
        cvt8(h8[(size_t)d * 8 + subl], acc);   // self-loop term
        int off = loff[i], c = lcnt[i];
        for (int j = 0; j < c; ++j) {
            int s = els[off + j];              // LDS broadcast across 8 lanes
            float v[8];
            cvt8(h8[(size_t)s * 8 + subl], v);
#pragma unroll
            for (int k = 0; k < 8; ++k) acc[k] += v[k];
        }
        float di = dinv[d];
        float o[8];
#pragma unroll
        for (int k = 0; k < 8; ++k) {
            o[k] = acc[k] * di;
            ps[k] += o[k];
            pq[k] = fmaf(o[k], o[k], pq[k]);
        }
        __half2 p0 = __floats2half2_rn(o[0], o[1]);
        __half2 p1 = __floats2half2_rn(o[2], o[3]);
        __half2 p2 = __floats2half2_rn(o[4], o[5]);
        __half2 p3 = __floats2half2_rn(o[6], o[7]);
        uint4 w; w.x = *(unsigned*)&p0; w.y = *(unsigned*)&p1;
        w.z = *(unsigned*)&p2; w.w = *(unsigned*)&p3;
        ((uint4*)out1)[(size_t)d * 8 + subl] = w;
    }
    // stats reduce: lanes sharing subl (xor bits 3..5), then cross-wave
#pragma unroll
    for (int mm = 8; mm < 64; mm <<= 1) {
#pragma unroll
        for (int k = 0; k < 8; ++k) {
            ps[k] += __shfl_xor(ps[k], mm);
            pq[k] += __shfl_xor(pq[k], mm);
        }
    }
    __shared__ float red[4][128];
    int lane = t & 63, wv = t >> 6;
    if (lane < 8) {
        int c0 = lane * 8;
#pragma unroll
        for (int k = 0; k < 8; ++k) {
            red[wv][c0 + k] = ps[k];
            red[wv][64 + c0 + k] = pq[k];
        }
    }
    __syncthreads();
    if (t < 128) {
        float v = red[0][t] + red[1][t] + red[2][t] + red[3][t];
        unsafeAtomicAdd(&stats[t], v);         // stats[c]=sum, stats[64+c]=sumsq
    }
}

// K5: s1 = relu(bn1(out1)); hs2 = (s1 @ w2) * dinv[row], via MFMA.
__global__ __launch_bounds__(256) void k7_xw2(
        const __half* __restrict__ out1, const float* __restrict__ stats,
        const float* __restrict__ g1, const float* __restrict__ beta1,
        const float* __restrict__ w2, const float* __restrict__ dinv,
        float* __restrict__ hs2) {
    __shared__ float lsc[64], lsh[64];
    int t = threadIdx.x;
    if (t < 64) {
        float invn = 1.f / (float)N_NODES;
        float m = stats[t] * invn;
        float v = stats[64 + t] * invn - m * m;
        float inv = rsqrtf(v + BN_EPS);
        float sc = g1[t] * inv;
        lsc[t] = sc;
        lsh[t] = beta1[t] - m * sc;
    }
    __syncthreads();
    int lane = t & 63, wv = t >> 6;
    int r = lane & 15, kb = lane >> 4;
    f16x8 bf[2];
    float scr[2][8], shr[2][8];
#pragma unroll
    for (int kh = 0; kh < 2; ++kh) {
        int k0 = kh * 32 + kb * 8;
        f16x8 b;
#pragma unroll
        for (int i = 0; i < 8; ++i) {
            b[i] = (r < 2) ? (_Float16)w2[(k0 + i) * 2 + r] : (_Float16)0.f;
            scr[kh][i] = lsc[k0 + i];
            shr[kh][i] = lsh[k0 + i];
        }
        bf[kh] = b;
    }
    const int NGRP = N_NODES / 16;             // 6250
    int wid = blockIdx.x * 4 + wv;
    for (int g = wid; g < NGRP; g += K7_NBLK * 4) {
        f32x4 acc; acc[0]=0.f; acc[1]=0.f; acc[2]=0.f; acc[3]=0.f;
#pragma unroll
        for (int kh = 0; kh < 2; ++kh) {
            uint4 av = *(const uint4*)(out1 + (size_t)(g * 16 + r) * 64 + kh * 32 + kb * 8);
            unsigned w[4] = {av.x, av.y, av.z, av.w};
            f16x8 a;
#pragma unroll
            for (int h = 0; h < 4; ++h) {
                float2 f = __half22float2(*(__half2*)&w[h]);
                float y0 = fmaxf(fmaf(f.x, scr[kh][2*h],   shr[kh][2*h]),   0.f);
                float y1 = fmaxf(fmaf(f.y, scr[kh][2*h+1], shr[kh][2*h+1]), 0.f);
                a[2*h]   = (_Float16)y0;
                a[2*h+1] = (_Float16)y1;
            }
            acc = __builtin_amdgcn_mfma_f32_16x16x32_f16(a, bf[kh], acc, 0, 0, 0);
        }
        if (r < 2) {
            float4 dv = *(const float4*)&dinv[g * 16 + kb * 4];
            float dvv[4] = {dv.x, dv.y, dv.z, dv.w};
#pragma unroll
            for (int reg = 0; reg < 4; ++reg) {
                int row = g * 16 + kb * 4 + reg;
                hs2[row * 2 + r] = acc[reg] * dvv[reg];
            }
        }
    }
}

// K6: layer-2 aggregation: same in-LDS sort, register gather (1 thread/node),
// fused BN2 stats.
__global__ __launch_bounds__(256) void k_pull2C(
        const int* __restrict__ gcur, const int* __restrict__ binned,
        const float* __restrict__ dinv, const float* __restrict__ hs2,
        float* __restrict__ out2, float* __restrict__ stats2) {
    int b = blockIdx.x, t = threadIdx.x;
    int nb0 = b * NPB;
    if (nb0 >= N_NODES) return;
    int nn = min(NPB, N_NODES - nb0);
    __shared__ int els[BCAP];
    __shared__ int lcnt[NPB], loff[NPB], lcur2[NPB];
    __shared__ int sc[256];
    for (int i = t; i < NPB; i += 256) lcnt[i] = 0;
    __syncthreads();
    int base = b * BCAP;
    int m = min(gcur[b] - base, BCAP);
    for (int j = t; j < m; j += 256)
        atomicAdd(&lcnt[((unsigned)binned[base + j]) >> 17], 1);
    __syncthreads();
    sc[t] = (t < nn) ? lcnt[t] : 0;
    __syncthreads();
    for (int off = 1; off < 256; off <<= 1) {
        int v = (t >= off) ? sc[t - off] : 0;
        __syncthreads();
        sc[t] += v;
        __syncthreads();
    }
    if (t < nn) { int e = sc[t] - lcnt[t]; loff[t] = e; lcur2[t] = e; }
    __syncthreads();
    for (int j = t; j < m; j += 256) {
        unsigned v = (unsigned)binned[base + j];
        int pos = atomicAdd(&lcur2[v >> 17], 1);
        els[pos] = (int)(v & 0x1FFFFu);
    }
    __syncthreads();
    const float2* h2 = (const float2*)hs2;
    float s0 = 0.f, s1 = 0.f, q0 = 0.f, q1 = 0.f;
    for (int i = t; i < nn; i += 256) {
        int d = nb0 + i;
        float2 self = h2[d];
        float o0 = self.x, o1 = self.y;
        int off = loff[i], c = lcnt[i];
        for (int j = 0; j < c; ++j) {
            float2 x = h2[els[off + j]];       // L2-resident (800 KB)
            o0 += x.x; o1 += x.y;
        }
        float di = dinv[d];
        o0 *= di; o1 *= di;
        ((float2*)out2)[d] = make_float2(o0, o1);
        s0 += o0; s1 += o1;
        q0 = fmaf(o0, o0, q0); q1 = fmaf(o1, o1, q1);
    }
#pragma unroll
    for (int mm = 32; mm; mm >>= 1) {
        s0 += __shfl_down(s0, mm); s1 += __shfl_down(s1, mm);
        q0 += __shfl_down(q0, mm); q1 += __shfl_down(q1, mm);
    }
    __shared__ float red[4][4];
    int wv = t >> 6;
    if ((t & 63) == 0) {
        red[0][wv] = s0; red[1][wv] = s1; red[2][wv] = q0; red[3][wv] = q1;
    }
    __syncthreads();
    if (t < 4) {
        float v = red[t][0] + red[t][1] + red[t][2] + red[t][3];
        unsafeAtomicAdd(&stats2[t], v);
    }
}

// K7: BN2 + sigmoid + softmax epilogue
__global__ __launch_bounds__(256) void k10_head(
        const float* __restrict__ out2, const float* __restrict__ stats2,
        const float* __restrict__ g2, const float* __restrict__ beta2,
        float* __restrict__ out) {
    int r = blockIdx.x * blockDim.x + threadIdx.x;
    if (r >= N_NODES) return;
    float invn = 1.f / (float)N_NODES;
    float m0 = stats2[0] * invn, m1 = stats2[1] * invn;
    float v0 = stats2[2] * invn - m0 * m0;
    float v1 = stats2[3] * invn - m1 * m1;
    float i0 = rsqrtf(v0 + BN_EPS), i1 = rsqrtf(v1 + BN_EPS);
    float sc0 = g2[0] * i0, sc1 = g2[1] * i1;
    float sh0 = beta2[0] - m0 * sc0, sh1 = beta2[1] - m1 * sc1;
    float2 x = ((const float2*)out2)[r];
    float y0 = fmaf(x.x, sc0, sh0), y1 = fmaf(x.y, sc1, sh1);
    out[r * 2] = 1.f / (1.f + __expf(-y0));
    out[r * 2 + 1] = 1.f / (1.f + __expf(-y1));
    out[2 * N_NODES + r * 2] = 1.f / (1.f + __expf(y1 - y0));
    out[2 * N_NODES + r * 2 + 1] = 1.f / (1.f + __expf(y0 - y1));
}

extern "C" void kernel_launch(void* const* d_in, const int* in_sizes, int n_in,
                              void* d_out, int out_size, void* d_ws, size_t ws_size,
                              hipStream_t stream) {
    const int*   edge  = (const int*)d_in[0];          // (2,E): [0,E)=src, [E,2E)=dst
    const float* u_S   = (const float*)d_in[1];
    const float* w1    = (const float*)d_in[2];
    const float* g1    = (const float*)d_in[4];
    const float* beta1 = (const float*)d_in[5];
    const float* w2    = (const float*)d_in[6];
    const float* g2    = (const float*)d_in[8];
    const float* beta2 = (const float*)d_in[9];
    float* out = (float*)d_out;

    float*  ws     = (float*)d_ws;
    int*    gcur   = (int*)(ws + OFF_GCUR);
    float*  stats1 = ws + OFF_STATS1;
    float*  stats2 = ws + OFF_STATS2;
    float*  dinv   = ws + OFF_DINV;
    int*    binned = (int*)(ws + OFF_BINNED);
    __half* hs1    = (__half*)(ws + OFF_HS1);
    __half* out1   = (__half*)(ws + OFF_OUT1);
    float*  hs2    = ws + OFF_HS2;
    float*  out2   = ws + OFF_OUT2;

    const int* src = edge;
    const int* dst = edge + N_EDGES;

    k0_init<<<1, 256, 0, stream>>>(gcur, stats1);
    k_bin<<<NBLK_BIN, 256, 0, stream>>>(src, dst, gcur, binned);
    k_deg<<<NBUCK_USED, 256, 0, stream>>>(gcur, binned, dinv);
    k3_xw1<<<(N_NODES / 16 + 3) / 4, 256, 0, stream>>>(u_S, w1, dinv, hs1);
    k_pull1C<<<NBUCK_USED, 256, 0, stream>>>(gcur, binned, dinv, hs1, out1, stats1);
    k7_xw2<<<K7_NBLK, 256, 0, stream>>>(out1, stats1, g1, beta1, w2, dinv, hs2);
    k_pull2C<<<NBUCK_USED, 256, 0, stream>>>(gcur, binned, dinv, hs2, out2, stats2);
    k10_head<<<(N_NODES + 255) / 256, 256, 0, stream>>>(out2, stats2, g2, beta2, out);
}